// Round 10
// baseline (62.479 us; speedup 1.0000x reference)
//
#include <hip/hip_runtime.h>

#define BATCH 4096
#define FEAT  2048
#define GRID  1024            // 4 rows per block (one per wave)
#define GROUPS 32             // level-2 fan-in
#define BPG    32             // blocks per group (level-1 fan-in), GROUPS*BPG == GRID

typedef float f32x4 __attribute__((ext_vector_type(4)));

// Fused single kernel + tiny memset node.
// ws layout: [0] level-2 counter | [1..32] level-1 counters | byte 256+: GRID partials.
// R5 lesson: ONE completion counter = 1024 serialized same-address RMWs (~50us).
// Here: 32x32 hierarchical counters -> chains run on 32 addresses in parallel and
// hide under k1's staggered block completions. Winner needs NO spin (acq-rel chain
// guarantees all partials visible). Deterministic: fixed-order summation.
__global__ __launch_bounds__(256) void center_loss_fused(
        const float* __restrict__ x,
        const int*   __restrict__ labels,
        const float* __restrict__ centers,
        unsigned int* __restrict__ counters,
        float*       __restrict__ partials,
        float*       __restrict__ out) {
    const int wave = threadIdx.x >> 6;
    const int lane = threadIdx.x & 63;
    const int row  = (blockIdx.x << 2) | wave;

    const int lbl = labels[row];                      // wave-uniform -> scalar load
    const f32x4* __restrict__ xr = (const f32x4*)(x + (size_t)row * FEAT) + lane;
    const f32x4* __restrict__ cr = (const f32x4*)(centers + (size_t)lbl * FEAT) + lane;

    // issue all 16 loads before any arithmetic
    f32x4 xv[8], cv[8];
#pragma unroll
    for (int i = 0; i < 8; ++i)
        xv[i] = __builtin_nontemporal_load(xr + (i << 6));   // x: streamed (keeps L2 for centers)
#pragma unroll
    for (int i = 0; i < 8; ++i)
        cv[i] = cr[i << 6];                                   // centers: cacheable

    float p = 0.f;
#pragma unroll
    for (int i = 0; i < 8; ++i) {
        f32x4 d = xv[i] - cv[i];
        p += d.x * d.x + d.y * d.y + d.z * d.z + d.w * d.w;
    }

    // wave-64 butterfly reduce
#pragma unroll
    for (int off = 32; off > 0; off >>= 1)
        p += __shfl_down(p, off, 64);

    __shared__ float sw[4];
    __shared__ int s_reduce;
    if (lane == 0) sw[wave] = p;
    __syncthreads();

    if (threadIdx.x == 0) {
        // clamp per ROW (reference semantics), then sum this block's 4 rows
        float s = fminf(fmaxf(sw[0], 1e-12f), 1e12f)
                + fminf(fmaxf(sw[1], 1e-12f), 1e12f)
                + fminf(fmaxf(sw[2], 1e-12f), 1e12f)
                + fminf(fmaxf(sw[3], 1e-12f), 1e12f);
        // device-coherent partial store (bypasses L1/L2 caching of stale replays)
        __hip_atomic_store(&partials[blockIdx.x], s,
                           __ATOMIC_RELAXED, __HIP_MEMORY_SCOPE_AGENT);
        int is_red = 0;
        const unsigned g = (unsigned)blockIdx.x >> 5;          // group id
        unsigned o1 = __hip_atomic_fetch_add(&counters[1 + g], 1u,
                           __ATOMIC_ACQ_REL, __HIP_MEMORY_SCOPE_AGENT);
        if (o1 == BPG - 1) {                                   // group complete
            unsigned o2 = __hip_atomic_fetch_add(&counters[0], 1u,
                           __ATOMIC_ACQ_REL, __HIP_MEMORY_SCOPE_AGENT);
            if (o2 == GROUPS - 1) is_red = 1;                  // all partials visible
        }
        s_reduce = is_red;
    }
    __syncthreads();

    if (s_reduce) {
        const int t = threadIdx.x;
        float s = 0.f;
#pragma unroll
        for (int i = 0; i < GRID / 256; ++i)                   // fixed order: deterministic
            s += __hip_atomic_load(&partials[t + i * 256],
                                   __ATOMIC_RELAXED, __HIP_MEMORY_SCOPE_AGENT);
#pragma unroll
        for (int off = 32; off > 0; off >>= 1)
            s += __shfl_down(s, off, 64);
        __shared__ float sw2[4];
        if ((t & 63) == 0) sw2[t >> 6] = s;
        __syncthreads();
        if (t == 0)
            out[0] = (sw2[0] + sw2[1] + sw2[2] + sw2[3]) * (1.0f / (float)BATCH);
    }
}

extern "C" void kernel_launch(void* const* d_in, const int* in_sizes, int n_in,
                              void* d_out, int out_size, void* d_ws, size_t ws_size,
                              hipStream_t stream) {
    const float* x       = (const float*)d_in[0];
    const int*   labels  = (const int*)d_in[1];
    const float* centers = (const float*)d_in[2];
    float* out = (float*)d_out;

    unsigned int* counters = (unsigned int*)d_ws;          // 33 uints
    float* partials = (float*)((char*)d_ws + 256);         // GRID floats

    hipMemsetAsync(d_ws, 0, 33 * sizeof(unsigned int), stream);
    center_loss_fused<<<GRID, 256, 0, stream>>>(x, labels, centers,
                                                counters, partials, out);
}

// Round 11
// 21.074 us; speedup vs baseline: 2.9648x; 2.9648x over previous
//
#include <hip/hip_runtime.h>

#define BATCH 4096
#define FEAT  2048
#define GRID  256            // 256 blocks x 1024 threads; 16 waves = 16 rows per block

typedef float f32x4 __attribute__((ext_vector_type(4)));
typedef unsigned long long u64;

#define CNT_SHIFT 53
#define VAL_MASK  ((1ULL << CNT_SHIFT) - 1)
#define FIX_SCALE 16777216.0f          // 2^24 fixed-point scale
// mean = total / 2^24 / BATCH = total / 2^36
#define INV_SCALE (1.0 / 68719476736.0)

// Fence-free fused reduction: each block's partial travels THROUGH a single
// relaxed u64 atomicAdd (low 53 bits: fixed-point value; high bits: arrival
// count). R10 evidence: per-block acq/rel fences serialize at ~58ns each
// (~60us for 1024) — relaxed RMWs emit no cache ops. Integer accumulation is
// order-independent -> bit-deterministic output. 256 blocks keeps the
// same-address RMW queue short (~256 ops, hidden under staggered completion).
__global__ __launch_bounds__(1024) void center_loss_fused(
        const float* __restrict__ x,
        const int*   __restrict__ labels,
        const float* __restrict__ centers,
        u64*         __restrict__ acc,
        float*       __restrict__ out) {
    const int wave = threadIdx.x >> 6;          // 0..15
    const int lane = threadIdx.x & 63;
    const int row  = (blockIdx.x << 4) | wave;  // one row per wave

    const int lbl = labels[row];                // wave-uniform -> scalar load
    const f32x4* __restrict__ xr = (const f32x4*)(x + (size_t)row * FEAT) + lane;
    const f32x4* __restrict__ cr = (const f32x4*)(centers + (size_t)lbl * FEAT) + lane;

    // issue all 16 loads before any arithmetic
    f32x4 xv[8], cv[8];
#pragma unroll
    for (int i = 0; i < 8; ++i)
        xv[i] = __builtin_nontemporal_load(xr + (i << 6));   // x: streamed (keeps L2 for centers)
#pragma unroll
    for (int i = 0; i < 8; ++i)
        cv[i] = cr[i << 6];                                   // centers: cacheable

    float p = 0.f;
#pragma unroll
    for (int i = 0; i < 8; ++i) {
        f32x4 d = xv[i] - cv[i];
        p += d.x * d.x + d.y * d.y + d.z * d.z + d.w * d.w;
    }

    // wave-64 butterfly reduce
#pragma unroll
    for (int off = 32; off > 0; off >>= 1)
        p += __shfl_down(p, off, 64);

    __shared__ float sw[16];
    if (lane == 0) sw[wave] = p;
    __syncthreads();

    if (threadIdx.x == 0) {
        // clamp per ROW (reference semantics), sum the block's 16 rows
        float s = 0.f;
#pragma unroll
        for (int i = 0; i < 16; ++i)
            s += fminf(fmaxf(sw[i], 1e-12f), 1e12f);

        const u64 q    = (u64)(s * FIX_SCALE + 0.5f);        // 53-bit fixed point
        const u64 pack = (1ULL << CNT_SHIFT) | q;
        const u64 old  = __hip_atomic_fetch_add(acc, pack,
                             __ATOMIC_RELAXED, __HIP_MEMORY_SCOPE_AGENT);
        if ((old >> CNT_SHIFT) == GRID - 1) {                // last arriver holds full sum
            const u64 total = (old & VAL_MASK) + q;
            out[0] = (float)((double)total * INV_SCALE);
        }
    }
}

extern "C" void kernel_launch(void* const* d_in, const int* in_sizes, int n_in,
                              void* d_out, int out_size, void* d_ws, size_t ws_size,
                              hipStream_t stream) {
    const float* x       = (const float*)d_in[0];
    const int*   labels  = (const int*)d_in[1];
    const float* centers = (const float*)d_in[2];
    float* out = (float*)d_out;
    u64*   acc = (u64*)d_ws;

    hipMemsetAsync(acc, 0, sizeof(u64), stream);
    center_loss_fused<<<GRID, 1024, 0, stream>>>(x, labels, centers, acc, out);
}